// Round 2
// baseline (6701.023 us; speedup 1.0000x reference)
//
#include <hip/hip_runtime.h>

typedef unsigned short u16;
typedef __attribute__((ext_vector_type(4))) float f32x4;
typedef __attribute__((ext_vector_type(8))) short bfrag;   // 8 x bf16 bits
typedef __attribute__((ext_vector_type(8))) unsigned short us8;

// ---------- helpers ----------
__device__ __forceinline__ u16 f2bf(float f) {
    union { float f; unsigned u; } v; v.f = f;
    unsigned r = v.u + 0x7fffu + ((v.u >> 16) & 1u);   // RNE
    return (u16)(r >> 16);
}
__device__ __forceinline__ float bf2f(u16 b) {
    union { unsigned u; float f; } v; v.u = ((unsigned)b) << 16;
    return v.f;
}
__device__ __forceinline__ float sigm(float x) { return 1.0f / (1.0f + __expf(-x)); }
__device__ __forceinline__ float tanh_(float x) { return 1.0f - 2.0f / (__expf(2.0f * x) + 1.0f); }

// ---------- phase A: convert x to bf16 ----------
__global__ __launch_bounds__(256) void pack_x(const float* __restrict__ x, u16* __restrict__ xbf) {
    int gid = blockIdx.x * 256 + threadIdx.x;          // 2,097,152 threads, 8 elems each
    size_t base = (size_t)gid * 8;
    const float4* xv = (const float4*)(x + base);
    float4 a = xv[0], b = xv[1];
    us8 r;
    r[0] = f2bf(a.x); r[1] = f2bf(a.y); r[2] = f2bf(a.z); r[3] = f2bf(a.w);
    r[4] = f2bf(b.x); r[5] = f2bf(b.y); r[6] = f2bf(b.z); r[7] = f2bf(b.w);
    *(us8*)(xbf + base) = r;
}

// ---------- phase A: zero h double-buffers + control (ws poisoned every call) ----------
__global__ __launch_bounds__(256) void zero_ctl(uint4* __restrict__ p) {
    int gid = blockIdx.x * 256 + threadIdx.x;          // zero 262,656 B = 16,416 uint4
    if (gid < 16416) p[gid] = make_uint4(0u, 0u, 0u, 0u);
}

// ---------- phase A: pack W into MFMA B-fragment layout ----------
// packed[dir][half][ntile(128)][ks(16)][lane(64)][8 bf16]
// element (nt,ks,lane,j) = W[half*512 + ks*32 + (lane>>4)*8 + j][nt*16 + (lane&15)]
__global__ __launch_bounds__(256) void pack_w(const float* __restrict__ Wf, const float* __restrict__ Wb,
                                              u16* __restrict__ wxp, u16* __restrict__ whp) {
    int g = blockIdx.x * 256 + threadIdx.x;            // 524,288 threads
    int lane = g & 63; g >>= 6;
    int ks = g & 15;  g >>= 4;
    int nt = g & 127; g >>= 7;
    int half = g & 1;
    int dir = g >> 1;
    const float* W = dir ? Wb : Wf;
    u16* dst = (half ? whp : wxp) + (size_t)dir * 1048576;
    int rowb = half * 512 + ks * 32 + (lane >> 4) * 8;
    int col  = nt * 16 + (lane & 15);
    us8 v;
#pragma unroll
    for (int j = 0; j < 8; ++j) v[j] = f2bf(W[(size_t)(rowb + j) * 2048 + col]);
    *(us8*)(dst + ((size_t)(nt * 16 + ks) * 64 + lane) * 8) = v;
}

// ---------- phase B: persistent recurrence, regular launch + hand-rolled barrier ----------
// 128 blocks launched; 64 claim roles (dir in {0,1} x j in [0,32)), rest exit.
// Block (dir, j): h-cols [j*16, j*16+16), all 64 batch rows, all 512 steps.
// Wave w (of 4) = batch rows [w*16, w*16+16). Computes all 4 gates for its tile.
// Wx slice (4 ntiles x 16 ks) staged in LDS (64 KB); Wh slice held in 256 VGPRs.
// ctrl layout (unsigned): [0],[1]=claim counters; [32],[64]=per-dir barrier counters.
__global__ __launch_bounds__(256, 1) void rnn_all(const u16* __restrict__ wxp, const u16* __restrict__ whp,
                                                  const u16* __restrict__ xbf,
                                                  const float* __restrict__ b_fw, const float* __restrict__ b_bw,
                                                  u16* __restrict__ hbuf, unsigned* __restrict__ ctrl,
                                                  float* __restrict__ out) {
    __shared__ u16 wx_lds[32768];     // 64 KB: [f=g*16+ks][lane][8]
    __shared__ int s_claim[2];
    int tid = threadIdx.x;

    if (tid == 0) {
        // XCC_ID (hwreg 20) — only a claim PREFERENCE; correctness holds for any value.
        unsigned xcd = __builtin_amdgcn_s_getreg(20 | (0 << 6) | (31 << 11));
        int role = -1, dir = 0;
        for (int a = 0; a < 2 && role < 0; ++a) {
            int d = ((int)xcd ^ a) & 1;
            unsigned r = atomicAdd(&ctrl[d], 1u);
            if (r < 32u) { role = (int)r; dir = d; }
        }
        s_claim[0] = role; s_claim[1] = dir;
    }
    __syncthreads();
    const int j = s_claim[0], dir = s_claim[1];
    if (j < 0) return;                 // surplus block

    const int widx = tid >> 6, lane = tid & 63, l15 = lane & 15, lhi = lane >> 4;
    const int m0 = widx * 16;
    const u16* wxs = wxp + (size_t)dir * 1048576;
    const u16* whs = whp + (size_t)dir * 1048576;

    // stage Wx slice -> LDS (ntiles g*32+j, g=0..3)
    for (int idx = tid; idx < 4096; idx += 256) {
        int f = idx >> 6, ln = idx & 63;
        int g = f >> 4, ks = f & 15;
        *(us8*)&wx_lds[f * 512 + ln * 8] =
            *(const us8*)&wxs[(size_t)(g * 32 + j) * 8192 + ks * 512 + ln * 8];
    }
    // Wh slice -> registers (64 fragments = 256 VGPR)
    bfrag wh[4][16];
#pragma unroll
    for (int g = 0; g < 4; ++g)
#pragma unroll
        for (int ks = 0; ks < 16; ++ks)
            wh[g][ks] = *(const bfrag*)&whs[(size_t)(g * 32 + j) * 8192 + ks * 512 + lane * 8];
    // bias (per gate, this thread's h-col)
    const float* bias = dir ? b_bw : b_fw;
    float bv[4];
#pragma unroll
    for (int g = 0; g < 4; ++g) bv[g] = bias[g * 512 + j * 16 + l15];
    __syncthreads();

    const u16* xb = xbf + (size_t)(m0 + l15) * 262144 + lhi * 8;   // x[b][t][k] base
    u16* hb_base = hbuf + (size_t)dir * 65536;
    unsigned* cnt = ctrl + 32 + dir * 32;

    float c[4] = {0.f, 0.f, 0.f, 0.f};
    const int row = m0 + lhi * 4;          // first of 4 batch rows this thread finalizes
    const int hcol = j * 16 + l15;

#pragma unroll 1
    for (int s = 0; s < 512; ++s) {
        int t = dir ? (511 - s) : s;
        f32x4 acc[4];
#pragma unroll
        for (int g = 0; g < 4; ++g) acc[g] = (f32x4){bv[g], bv[g], bv[g], bv[g]};

        // x-part: z += x_t @ Wx   (A from global xbf, B from LDS)
        const u16* xt = xb + t * 512;
#pragma unroll
        for (int ks = 0; ks < 16; ++ks) {
            bfrag ax = *(const bfrag*)(xt + ks * 32);
#pragma unroll
            for (int g = 0; g < 4; ++g)
                acc[g] = __builtin_amdgcn_mfma_f32_16x16x32_bf16(
                    ax, *(const bfrag*)&wx_lds[(g * 16 + ks) * 512 + lane * 8], acc[g], 0, 0, 0);
        }
        // h-part: z += h_{t-1} @ Wh   (A from global h buffer, B from registers)
        const u16* hb = hb_base + (s & 1) * 32768 + (size_t)(m0 + l15) * 512 + lhi * 8;
#pragma unroll
        for (int ks = 0; ks < 16; ++ks) {
            bfrag ah = *(const bfrag*)(hb + ks * 32);
#pragma unroll
            for (int g = 0; g < 4; ++g)
                acc[g] = __builtin_amdgcn_mfma_f32_16x16x32_bf16(ah, wh[g][ks], acc[g], 0, 0, 0);
        }
        // finalize: gates i,j,f,o = acc[0..3]
        u16* hw = hb_base + ((s & 1) ^ 1) * 32768;
#pragma unroll
        for (int r = 0; r < 4; ++r) {
            float cn = sigm(acc[2][r] + 1.0f) * c[r] + sigm(acc[0][r]) * tanh_(acc[1][r]);
            c[r] = cn;
            float h = sigm(acc[3][r]) * tanh_(cn);
            out[(size_t)((row + r) * 512 + t) * 1024 + dir * 512 + hcol] = h;
            hw[(row + r) * 512 + hcol] = f2bf(h);
        }
        if (s == 511) break;

        // per-direction grid barrier (32 blocks, monotonic counter)
        __syncthreads();                       // drains vmcnt for all threads' h stores
        if (tid == 0) {
            __threadfence();                   // release: L2 writeback (agent scope)
            atomicAdd(cnt, 1u);
            unsigned target = 32u * (unsigned)(s + 1);
            while (__hip_atomic_load(cnt, __ATOMIC_RELAXED, __HIP_MEMORY_SCOPE_AGENT) < target)
                __builtin_amdgcn_s_sleep(1);
            __threadfence();                   // acquire: cache invalidate
        }
        __syncthreads();
    }
}

// ---------- launcher ----------
extern "C" void kernel_launch(void* const* d_in, const int* in_sizes, int n_in,
                              void* d_out, int out_size, void* d_ws, size_t ws_size,
                              hipStream_t stream) {
    (void)in_sizes; (void)n_in; (void)out_size;
    const float* x  = (const float*)d_in[0];
    const float* Wf = (const float*)d_in[1];
    const float* bf = (const float*)d_in[2];
    const float* Wb = (const float*)d_in[3];
    const float* bb = (const float*)d_in[4];
    float* out = (float*)d_out;

    // workspace layout (bytes), total 42,205,696
    const size_t o_wx  = 0;                    //  4,194,304  packed W_x (2 dirs)
    const size_t o_wh  = 4194304;              //  4,194,304  packed W_h (2 dirs)
    const size_t o_hb  = 8388608;              //    262,144  h double buffers (2 dirs x 2)
    const size_t o_ct  = 8650752;              //        512  claim + barrier counters
    const size_t o_xbf = 8651264;              // 33,554,432  x in bf16
    const size_t need  = o_xbf + 33554432;
    if (ws_size < need) return;

    char* ws = (char*)d_ws;
    u16* wxp = (u16*)(ws + o_wx);
    u16* whp = (u16*)(ws + o_wh);
    u16* hb  = (u16*)(ws + o_hb);
    unsigned* ctl = (unsigned*)(ws + o_ct);
    u16* xbf = (u16*)(ws + o_xbf);

    hipLaunchKernelGGL(pack_x, dim3(8192), dim3(256), 0, stream, x, xbf);
    hipLaunchKernelGGL(zero_ctl, dim3(65), dim3(256), 0, stream, (uint4*)(ws + o_hb));
    hipLaunchKernelGGL(pack_w, dim3(2048), dim3(256), 0, stream, Wf, Wb, wxp, whp);
    hipLaunchKernelGGL(rnn_all, dim3(128), dim3(256), 0, stream,
                       wxp, whp, xbf, bf, bb, hb, ctl, out);
}